// Round 13
// baseline (148.160 us; speedup 1.0000x reference)
//
#include <hip/hip_runtime.h>
#include <math.h>

#define NB    32
#define SEQ   2048
#define HD    1024
#define CDIM  256
#define NATTN 512
#define RECF  1028         // floats per partial record: 1024 ctx + 1 denom + pad (16B aligned)

__device__ __forceinline__ float dot4(float4 a, float4 b) {
    return a.x*b.x + a.y*b.y + a.z*b.z + a.w*b.w;
}

// ---------------- attention: wave w handles batch b=w&31, rows j, j+64, ... (j=w>>5).
// Measured r7: ~23.3us/pass alone — streaming-bound. Softmax is h_new-independent
// (constant per-row shift cancels); scores tiny -> exp(v) safe without max-tracking.
__device__ void attn_wave(int wid, const float* __restrict__ enc,
                          const int* __restrict__ lens, const float* __restrict__ attn_w,
                          float* __restrict__ part)
{
    int b = wid & 31, j = wid >> 5;
    int lane = threadIdx.x & 63;
    int len  = lens[b];

    float4 we0 = *(const float4*)(attn_w       + lane * 4);
    float4 we1 = *(const float4*)(attn_w + 256 + lane * 4);
    float4 we2 = *(const float4*)(attn_w + 512 + lane * 4);
    float4 we3 = *(const float4*)(attn_w + 768 + lane * 4);
    float4 c0 = make_float4(0,0,0,0), c1 = c0, c2 = c0, c3 = c0;
    float l = 0.f;

    const float* ebase = enc + (size_t)b * SEQ * HD + lane * 4;
    for (int s = j; s < len; s += 64) {
        const float* ep = ebase + (size_t)s * HD;
        float4 e0 = *(const float4*)(ep);
        float4 e1 = *(const float4*)(ep + 256);
        float4 e2 = *(const float4*)(ep + 512);
        float4 e3 = *(const float4*)(ep + 768);
        float v = dot4(e0,we0) + dot4(e1,we1) + dot4(e2,we2) + dot4(e3,we3);
        #pragma unroll
        for (int off = 32; off > 0; off >>= 1) v += __shfl_xor(v, off, 64);
        float p = __expf(v);
        l += p;
        c0.x += p*e0.x; c0.y += p*e0.y; c0.z += p*e0.z; c0.w += p*e0.w;
        c1.x += p*e1.x; c1.y += p*e1.y; c1.z += p*e1.z; c1.w += p*e1.w;
        c2.x += p*e2.x; c2.y += p*e2.y; c2.z += p*e2.z; c2.w += p*e2.w;
        c3.x += p*e3.x; c3.y += p*e3.y; c3.z += p*e3.z; c3.w += p*e3.w;
    }
    float* rec = part + (size_t)(b * 64 + j) * RECF;
    *(float4*)(rec +       lane * 4) = c0;
    *(float4*)(rec + 256 + lane * 4) = c1;
    *(float4*)(rec + 512 + lane * 4) = c2;
    *(float4*)(rec + 768 + lane * 4) = c3;
    if (lane == 0) rec[1024] = l;
}

// ---------------- gemm0 (LSTM): X=[emb|h_prev] 32x1280, W=[w_ih|w_hh] 4096x1280.
// Block = 32b x 128n, KSPLIT=8 (KRANGE=160) -> 256 units. Thread micro-tile 4b x 4n.
__device__ void gemm0_body(int gid,
                           const float* __restrict__ emb, const int* __restrict__ chars,
                           const float* __restrict__ h_prev,
                           const float* __restrict__ w_ih, const float* __restrict__ w_hh,
                           float* __restrict__ zpart)
{
    __shared__ float Xs[32][36];    // [k][b], pad keeps 16B alignment
    __shared__ float Ws[32][132];   // [k][n]

    const int nt = gid & 31;
    const int ky = gid >> 5;
    const int n0 = nt * 128;
    const int kbase = ky * 160;

    const int t  = threadIdx.x;
    const int nn = t & 31;
    const int bb = t >> 5;

    float4 acc0 = make_float4(0,0,0,0), acc1 = acc0, acc2 = acc0, acc3 = acc0;

    const int xb = t >> 3, xk = (t & 7) * 4;
    const int wn = t >> 3, wk = (t & 7) * 4;

    for (int k0 = kbase; k0 < kbase + 160; k0 += 32) {
        {
            int k = k0 + xk;
            float4 xv;
            if (k < CDIM) xv = *(const float4*)(emb + chars[xb] * CDIM + k);
            else          xv = *(const float4*)(h_prev + xb * HD + (k - CDIM));
            Xs[xk+0][xb] = xv.x; Xs[xk+1][xb] = xv.y; Xs[xk+2][xb] = xv.z; Xs[xk+3][xb] = xv.w;
        }
        #pragma unroll
        for (int i = 0; i < 4; ++i) {
            int n = n0 + wn + 32 * i;
            int k = k0 + wk;
            float4 wv;
            if (k < CDIM) wv = *(const float4*)(w_ih + n * CDIM + k);
            else          wv = *(const float4*)(w_hh + n * HD + (k - CDIM));
            int nc = wn + 32 * i;
            Ws[wk+0][nc] = wv.x; Ws[wk+1][nc] = wv.y; Ws[wk+2][nc] = wv.z; Ws[wk+3][nc] = wv.w;
        }
        __syncthreads();
        #pragma unroll
        for (int k = 0; k < 32; ++k) {
            float4 xv = *(const float4*)&Xs[k][bb * 4];
            float4 wv = *(const float4*)&Ws[k][nn * 4];
            acc0.x += xv.x*wv.x; acc0.y += xv.x*wv.y; acc0.z += xv.x*wv.z; acc0.w += xv.x*wv.w;
            acc1.x += xv.y*wv.x; acc1.y += xv.y*wv.y; acc1.z += xv.y*wv.z; acc1.w += xv.y*wv.w;
            acc2.x += xv.z*wv.x; acc2.y += xv.z*wv.y; acc2.z += xv.z*wv.z; acc2.w += xv.z*wv.w;
            acc3.x += xv.w*wv.x; acc3.y += xv.w*wv.y; acc3.z += xv.w*wv.z; acc3.w += xv.w*wv.w;
        }
        __syncthreads();
    }
    float* zr = zpart + (size_t)(ky * 32 + bb * 4) * 4096 + n0 + nn * 4;
    *(float4*)(zr           ) = acc0;
    *(float4*)(zr + 4096    ) = acc1;
    *(float4*)(zr + 4096 * 2) = acc2;
    *(float4*)(zr + 4096 * 3) = acc3;
}

// ---------------- K1: attn (blocks 0..511) ∪ LSTM gemm (blocks 512..767) — r8 exact
__global__ void __launch_bounds__(256) attn_gemm0(
    const float* __restrict__ enc, const int* __restrict__ lens,
    const float* __restrict__ attn_w, float* __restrict__ part,
    const float* __restrict__ emb, const int* __restrict__ chars,
    const float* __restrict__ h_prev,
    const float* __restrict__ w_ih, const float* __restrict__ w_hh,
    float* __restrict__ zpart)
{
    if (blockIdx.x < NATTN)
        attn_wave(blockIdx.x * 4 + (threadIdx.x >> 6), enc, lens, attn_w, part);
    else
        gemm0_body(blockIdx.x - NATTN, emb, chars, h_prev, w_ih, w_hh, zpart);
}

// ---------------- K2: LSTM gate epilogue (blocks 0..127) ∪ attention combine (128..255)
__global__ void gates_combine(const float* __restrict__ zpart,
                              const float* __restrict__ b_ih, const float* __restrict__ b_hh,
                              const float* __restrict__ c_prev, const float* __restrict__ part,
                              float* __restrict__ d_out, float* __restrict__ xcat2)
{
    int t = threadIdx.x;
    if (blockIdx.x < 128) {
        int idx = blockIdx.x * 256 + t;           // 32*1024
        int b = idx >> 10, j = idx & 1023;
        float z[4];
        #pragma unroll
        for (int g = 0; g < 4; ++g) {
            int n = g * 1024 + j;
            float v = b_ih[n] + b_hh[n];
            #pragma unroll
            for (int s = 0; s < 8; ++s) v += zpart[(size_t)(s * 32 + b) * 4096 + n];
            z[g] = v;
        }
        float gi = 1.f / (1.f + __expf(-z[0]));
        float gf = 1.f / (1.f + __expf(-z[1]));
        float gg = tanhf(z[2]);
        float go = 1.f / (1.f + __expf(-z[3]));
        float c = gf * c_prev[idx] + gi * gg;
        float h = go * tanhf(c);
        d_out[2048 + idx]         = h;            // h_new
        d_out[2048 + 32768 + idx] = c;            // c_new
        xcat2[b * 2048 + 1024 + j] = h;
    } else {
        int bid = blockIdx.x - 128;
        int b = bid >> 2, slice = bid & 3;
        int hh = slice * 256 + t;
        float acc = 0.f, L = 0.f;
        #pragma unroll 4
        for (int i = 0; i < 64; ++i) {
            const float* rec = part + (size_t)(b * 64 + i) * RECF;
            acc += rec[hh];
            L   += rec[1024];
        }
        xcat2[b * 2048 + hh] = acc / L;
    }
}

// ---------------- K3: concat projection split-K (32b x 128n, KSPLIT=16) -> 128 blocks
__global__ void __launch_bounds__(256) gemm_concat(
    const float* __restrict__ xcat2, const float* __restrict__ concat_w,
    float* __restrict__ nhpart)
{
    __shared__ float Xs[32][36];
    __shared__ float Ws[32][132];

    const int gid = blockIdx.x;
    const int nt = gid & 7;
    const int ky = gid >> 3;
    const int n0 = nt * 128;
    const int kbase = ky * 128;

    const int t  = threadIdx.x;
    const int nn = t & 31;
    const int bb = t >> 5;

    float4 acc0 = make_float4(0,0,0,0), acc1 = acc0, acc2 = acc0, acc3 = acc0;

    const int xb = t >> 3, xk = (t & 7) * 4;
    const int wn = t >> 3, wk = (t & 7) * 4;

    for (int k0 = kbase; k0 < kbase + 128; k0 += 32) {
        {
            float4 xv = *(const float4*)(xcat2 + xb * 2048 + k0 + xk);
            Xs[xk+0][xb] = xv.x; Xs[xk+1][xb] = xv.y; Xs[xk+2][xb] = xv.z; Xs[xk+3][xb] = xv.w;
        }
        #pragma unroll
        for (int i = 0; i < 4; ++i) {
            int n = n0 + wn + 32 * i;
            float4 wv = *(const float4*)(concat_w + n * 2048 + k0 + wk);
            int nc = wn + 32 * i;
            Ws[wk+0][nc] = wv.x; Ws[wk+1][nc] = wv.y; Ws[wk+2][nc] = wv.z; Ws[wk+3][nc] = wv.w;
        }
        __syncthreads();
        #pragma unroll
        for (int k = 0; k < 32; ++k) {
            float4 xv = *(const float4*)&Xs[k][bb * 4];
            float4 wv = *(const float4*)&Ws[k][nn * 4];
            acc0.x += xv.x*wv.x; acc0.y += xv.x*wv.y; acc0.z += xv.x*wv.z; acc0.w += xv.x*wv.w;
            acc1.x += xv.y*wv.x; acc1.y += xv.y*wv.y; acc1.z += xv.y*wv.z; acc1.w += xv.y*wv.w;
            acc2.x += xv.z*wv.x; acc2.y += xv.z*wv.y; acc2.z += xv.z*wv.z; acc2.w += xv.z*wv.w;
            acc3.x += xv.w*wv.x; acc3.y += xv.w*wv.y; acc3.z += xv.w*wv.z; acc3.w += xv.w*wv.w;
        }
        __syncthreads();
    }
    float* nr = nhpart + (size_t)(ky * 32 + bb * 4) * 1024 + n0 + nn * 4;
    *(float4*)(nr           ) = acc0;
    *(float4*)(nr + 1024    ) = acc1;
    *(float4*)(nr + 1024 * 2) = acc2;
    *(float4*)(nr + 1024 * 3) = acc3;
}

// ---------------- K4: nh = tanh(Σ 16 partials + b), then vocab projection — one block per b
__global__ void nh_out(const float* __restrict__ nhpart, const float* __restrict__ concat_b,
                       const float* __restrict__ out_w, const float* __restrict__ out_b,
                       float* __restrict__ d_out)
{
    int b = blockIdx.x, t = threadIdx.x;
    __shared__ float nh[1024];
    #pragma unroll
    for (int j = 0; j < 4; ++j) {
        int n = t + j * 256;
        float v = concat_b[n];
        #pragma unroll
        for (int s = 0; s < 16; ++s) v += nhpart[(size_t)(s * 32 + b) * 1024 + n];
        nh[n] = tanhf(v);
    }
    __syncthreads();
    int w = t >> 6, lane = t & 63;
    const float* nr = nh + lane * 4;
    #pragma unroll
    for (int vv = 0; vv < 16; ++vv) {
        int v = w * 16 + vv;
        const float* wr = out_w + v * 1024 + lane * 4;
        float acc = 0.f;
        #pragma unroll
        for (int i = 0; i < 4; ++i) {
            float4 wv = *(const float4*)(wr + i * 256);
            float4 nv = *(const float4*)(nr + i * 256);
            acc += dot4(wv, nv);
        }
        #pragma unroll
        for (int off = 32; off > 0; off >>= 1) acc += __shfl_xor(acc, off, 64);
        if (lane == 0) d_out[b * 64 + v] = acc + out_b[v];
    }
}

extern "C" void kernel_launch(void* const* d_in, const int* in_sizes, int n_in,
                              void* d_out, int out_size, void* d_ws, size_t ws_size,
                              hipStream_t stream)
{
    const int*   chars    = (const int*)  d_in[0];
    const float* h_prev   = (const float*)d_in[1];
    const float* c_prev   = (const float*)d_in[2];
    const int*   lens     = (const int*)  d_in[3];
    const float* enc      = (const float*)d_in[4];
    const float* emb      = (const float*)d_in[5];
    const float* w_ih     = (const float*)d_in[6];
    const float* w_hh     = (const float*)d_in[7];
    const float* b_ih     = (const float*)d_in[8];
    const float* b_hh     = (const float*)d_in[9];
    const float* attn_w   = (const float*)d_in[10];
    const float* concat_w = (const float*)d_in[12];
    const float* concat_b = (const float*)d_in[13];
    const float* out_w    = (const float*)d_in[14];
    const float* out_b    = (const float*)d_in[15];
    float* out = (float*)d_out;

    float* ws = (float*)d_ws;
    float* zpart  = ws;                      // 8*32*4096   = 1048576
    float* xcat2  = zpart + 1048576;         // 32*2048     = 65536
    float* part   = xcat2 + 65536;           // 2048*RECF   = 2105344
    float* nhpart = part + 2105344;          // 16*32*1024  = 524288

    // K1: attention (strided rows, ~23us streaming-bound) ∪ LSTM gemm (hidden?) — r8 exact
    attn_gemm0<<<dim3(NATTN + 256), 256, 0, stream>>>(enc, lens, attn_w, part,
                                                      emb, chars, h_prev, w_ih, w_hh, zpart);
    // K2: LSTM gate epilogue ∪ attention record-combine -> xcat2 = [context | h_new]
    gates_combine<<<dim3(256), 256, 0, stream>>>(zpart, b_ih, b_hh, c_prev, part, out, xcat2);
    // K3: concat projection split-K partials
    gemm_concat<<<dim3(128), 256, 0, stream>>>(xcat2, concat_w, nhpart);
    // K4: nh reduce+tanh fused with vocab projection
    nh_out<<<dim3(32), 256, 0, stream>>>(nhpart, concat_b, out_w, out_b, out);

    // PROFILE PROBE: repeat K1 3x (idempotent — rewrites part/zpart with identical values
    // from unmodified inputs; d_out untouched). T_K1 = (dur - 62.6)/3 decides whether
    // gemm0 contention (T_K1 >= 33) or the K2-K4 chain (T_K1 <= 28) is the next target.
    for (int rep = 0; rep < 3; ++rep) {
        attn_gemm0<<<dim3(NATTN + 256), 256, 0, stream>>>(enc, lens, attn_w, part,
                                                          emb, chars, h_prev, w_ih, w_hh, zpart);
    }
}

// Round 14
// 52.784 us; speedup vs baseline: 2.8069x; 2.8069x over previous
//
#include <hip/hip_runtime.h>
#include <math.h>

#define NB    32
#define SEQ   2048
#define HD    1024
#define CDIM  256
#define NATTN 512
#define RECF  1028         // floats per partial record: 1024 ctx + 1 denom + pad (16B aligned)

__device__ __forceinline__ float dot4(float4 a, float4 b) {
    return a.x*b.x + a.y*b.y + a.z*b.z + a.w*b.w;
}

// ---------------- attention: wave w handles batch b=w&31, rows j, j+64, ... (j=w>>5).
// Measured r7/r13: ~23.3us/pass in-situ 28.5 with gemm0 union — streaming-bound.
// Softmax h_new-independent (constant shift cancels); scores tiny -> exp(v) safe.
__device__ void attn_wave(int wid, const float* __restrict__ enc,
                          const int* __restrict__ lens, const float* __restrict__ attn_w,
                          float* __restrict__ part)
{
    int b = wid & 31, j = wid >> 5;
    int lane = threadIdx.x & 63;
    int len  = lens[b];

    float4 we0 = *(const float4*)(attn_w       + lane * 4);
    float4 we1 = *(const float4*)(attn_w + 256 + lane * 4);
    float4 we2 = *(const float4*)(attn_w + 512 + lane * 4);
    float4 we3 = *(const float4*)(attn_w + 768 + lane * 4);
    float4 c0 = make_float4(0,0,0,0), c1 = c0, c2 = c0, c3 = c0;
    float l = 0.f;

    const float* ebase = enc + (size_t)b * SEQ * HD + lane * 4;
    for (int s = j; s < len; s += 64) {
        const float* ep = ebase + (size_t)s * HD;
        float4 e0 = *(const float4*)(ep);
        float4 e1 = *(const float4*)(ep + 256);
        float4 e2 = *(const float4*)(ep + 512);
        float4 e3 = *(const float4*)(ep + 768);
        float v = dot4(e0,we0) + dot4(e1,we1) + dot4(e2,we2) + dot4(e3,we3);
        #pragma unroll
        for (int off = 32; off > 0; off >>= 1) v += __shfl_xor(v, off, 64);
        float p = __expf(v);
        l += p;
        c0.x += p*e0.x; c0.y += p*e0.y; c0.z += p*e0.z; c0.w += p*e0.w;
        c1.x += p*e1.x; c1.y += p*e1.y; c1.z += p*e1.z; c1.w += p*e1.w;
        c2.x += p*e2.x; c2.y += p*e2.y; c2.z += p*e2.z; c2.w += p*e2.w;
        c3.x += p*e3.x; c3.y += p*e3.y; c3.z += p*e3.z; c3.w += p*e3.w;
    }
    float* rec = part + (size_t)(b * 64 + j) * RECF;
    *(float4*)(rec +       lane * 4) = c0;
    *(float4*)(rec + 256 + lane * 4) = c1;
    *(float4*)(rec + 512 + lane * 4) = c2;
    *(float4*)(rec + 768 + lane * 4) = c3;
    if (lane == 0) rec[1024] = l;
}

// ---------------- gemm0 (LSTM): X=[emb|h_prev] 32x1280, W=[w_ih|w_hh] 4096x1280.
// Block = 32b x 128n, KSPLIT=8 (KRANGE=160) -> 256 units. Thread micro-tile 4b x 4n.
__device__ void gemm0_body(int gid,
                           const float* __restrict__ emb, const int* __restrict__ chars,
                           const float* __restrict__ h_prev,
                           const float* __restrict__ w_ih, const float* __restrict__ w_hh,
                           float* __restrict__ zpart)
{
    __shared__ float Xs[32][36];    // [k][b], pad keeps 16B alignment
    __shared__ float Ws[32][132];   // [k][n]

    const int nt = gid & 31;
    const int ky = gid >> 5;
    const int n0 = nt * 128;
    const int kbase = ky * 160;

    const int t  = threadIdx.x;
    const int nn = t & 31;
    const int bb = t >> 5;

    float4 acc0 = make_float4(0,0,0,0), acc1 = acc0, acc2 = acc0, acc3 = acc0;

    const int xb = t >> 3, xk = (t & 7) * 4;
    const int wn = t >> 3, wk = (t & 7) * 4;

    for (int k0 = kbase; k0 < kbase + 160; k0 += 32) {
        {
            int k = k0 + xk;
            float4 xv;
            if (k < CDIM) xv = *(const float4*)(emb + chars[xb] * CDIM + k);
            else          xv = *(const float4*)(h_prev + xb * HD + (k - CDIM));
            Xs[xk+0][xb] = xv.x; Xs[xk+1][xb] = xv.y; Xs[xk+2][xb] = xv.z; Xs[xk+3][xb] = xv.w;
        }
        #pragma unroll
        for (int i = 0; i < 4; ++i) {
            int n = n0 + wn + 32 * i;
            int k = k0 + wk;
            float4 wv;
            if (k < CDIM) wv = *(const float4*)(w_ih + n * CDIM + k);
            else          wv = *(const float4*)(w_hh + n * HD + (k - CDIM));
            int nc = wn + 32 * i;
            Ws[wk+0][nc] = wv.x; Ws[wk+1][nc] = wv.y; Ws[wk+2][nc] = wv.z; Ws[wk+3][nc] = wv.w;
        }
        __syncthreads();
        #pragma unroll
        for (int k = 0; k < 32; ++k) {
            float4 xv = *(const float4*)&Xs[k][bb * 4];
            float4 wv = *(const float4*)&Ws[k][nn * 4];
            acc0.x += xv.x*wv.x; acc0.y += xv.x*wv.y; acc0.z += xv.x*wv.z; acc0.w += xv.x*wv.w;
            acc1.x += xv.y*wv.x; acc1.y += xv.y*wv.y; acc1.z += xv.y*wv.z; acc1.w += xv.y*wv.w;
            acc2.x += xv.z*wv.x; acc2.y += xv.z*wv.y; acc2.z += xv.z*wv.z; acc2.w += xv.z*wv.w;
            acc3.x += xv.w*wv.x; acc3.y += xv.w*wv.y; acc3.z += xv.w*wv.z; acc3.w += xv.w*wv.w;
        }
        __syncthreads();
    }
    float* zr = zpart + (size_t)(ky * 32 + bb * 4) * 4096 + n0 + nn * 4;
    *(float4*)(zr           ) = acc0;
    *(float4*)(zr + 4096    ) = acc1;
    *(float4*)(zr + 4096 * 2) = acc2;
    *(float4*)(zr + 4096 * 3) = acc3;
}

// ---------------- K1: attn (blocks 0..511) ∪ LSTM gemm (blocks 512..767) — r8 exact
__global__ void __launch_bounds__(256) attn_gemm0(
    const float* __restrict__ enc, const int* __restrict__ lens,
    const float* __restrict__ attn_w, float* __restrict__ part,
    const float* __restrict__ emb, const int* __restrict__ chars,
    const float* __restrict__ h_prev,
    const float* __restrict__ w_ih, const float* __restrict__ w_hh,
    float* __restrict__ zpart)
{
    if (blockIdx.x < NATTN)
        attn_wave(blockIdx.x * 4 + (threadIdx.x >> 6), enc, lens, attn_w, part);
    else
        gemm0_body(blockIdx.x - NATTN, emb, chars, h_prev, w_ih, w_hh, zpart);
}

// ---------------- K2: LSTM gate epilogue (blocks 0..127) ∪ attention combine (128..255)
// combine: FULL unroll -> 128 independent loads in flight (~2 latency rounds, was ~16)
__global__ void gates_combine(const float* __restrict__ zpart,
                              const float* __restrict__ b_ih, const float* __restrict__ b_hh,
                              const float* __restrict__ c_prev, const float* __restrict__ part,
                              float* __restrict__ d_out, float* __restrict__ xcat2)
{
    int t = threadIdx.x;
    if (blockIdx.x < 128) {
        int idx = blockIdx.x * 256 + t;           // 32*1024
        int b = idx >> 10, j = idx & 1023;
        float z[4];
        #pragma unroll
        for (int g = 0; g < 4; ++g) {
            int n = g * 1024 + j;
            float v = b_ih[n] + b_hh[n];
            #pragma unroll
            for (int s = 0; s < 8; ++s) v += zpart[(size_t)(s * 32 + b) * 4096 + n];
            z[g] = v;
        }
        float gi = 1.f / (1.f + __expf(-z[0]));
        float gf = 1.f / (1.f + __expf(-z[1]));
        float gg = tanhf(z[2]);
        float go = 1.f / (1.f + __expf(-z[3]));
        float c = gf * c_prev[idx] + gi * gg;
        float h = go * tanhf(c);
        d_out[2048 + idx]         = h;            // h_new
        d_out[2048 + 32768 + idx] = c;            // c_new
        xcat2[b * 2048 + 1024 + j] = h;
    } else {
        int bid = blockIdx.x - 128;
        int b = bid >> 2, slice = bid & 3;
        int hh = slice * 256 + t;
        const float* recbase = part + (size_t)b * 64 * RECF;
        float a0 = 0.f, a1 = 0.f, a2 = 0.f, a3 = 0.f;
        float l0 = 0.f, l1 = 0.f, l2 = 0.f, l3 = 0.f;
        #pragma unroll
        for (int i = 0; i < 64; i += 4) {         // fully unrolled, 8 parallel accumulators
            a0 += recbase[(size_t)(i+0) * RECF + hh];
            a1 += recbase[(size_t)(i+1) * RECF + hh];
            a2 += recbase[(size_t)(i+2) * RECF + hh];
            a3 += recbase[(size_t)(i+3) * RECF + hh];
            l0 += recbase[(size_t)(i+0) * RECF + 1024];
            l1 += recbase[(size_t)(i+1) * RECF + 1024];
            l2 += recbase[(size_t)(i+2) * RECF + 1024];
            l3 += recbase[(size_t)(i+3) * RECF + 1024];
        }
        xcat2[b * 2048 + hh] = (a0 + a1 + a2 + a3) / (l0 + l1 + l2 + l3);
    }
}

// ---------------- K3: concat projection split-K (32b x 128n, KSPLIT=16) -> 128 blocks
__global__ void __launch_bounds__(256) gemm_concat(
    const float* __restrict__ xcat2, const float* __restrict__ concat_w,
    float* __restrict__ nhpart)
{
    __shared__ float Xs[32][36];
    __shared__ float Ws[32][132];

    const int gid = blockIdx.x;
    const int nt = gid & 7;
    const int ky = gid >> 3;
    const int n0 = nt * 128;
    const int kbase = ky * 128;

    const int t  = threadIdx.x;
    const int nn = t & 31;
    const int bb = t >> 5;

    float4 acc0 = make_float4(0,0,0,0), acc1 = acc0, acc2 = acc0, acc3 = acc0;

    const int xb = t >> 3, xk = (t & 7) * 4;
    const int wn = t >> 3, wk = (t & 7) * 4;

    for (int k0 = kbase; k0 < kbase + 128; k0 += 32) {
        {
            float4 xv = *(const float4*)(xcat2 + xb * 2048 + k0 + xk);
            Xs[xk+0][xb] = xv.x; Xs[xk+1][xb] = xv.y; Xs[xk+2][xb] = xv.z; Xs[xk+3][xb] = xv.w;
        }
        #pragma unroll
        for (int i = 0; i < 4; ++i) {
            int n = n0 + wn + 32 * i;
            float4 wv = *(const float4*)(concat_w + n * 2048 + k0 + wk);
            int nc = wn + 32 * i;
            Ws[wk+0][nc] = wv.x; Ws[wk+1][nc] = wv.y; Ws[wk+2][nc] = wv.z; Ws[wk+3][nc] = wv.w;
        }
        __syncthreads();
        #pragma unroll
        for (int k = 0; k < 32; ++k) {
            float4 xv = *(const float4*)&Xs[k][bb * 4];
            float4 wv = *(const float4*)&Ws[k][nn * 4];
            acc0.x += xv.x*wv.x; acc0.y += xv.x*wv.y; acc0.z += xv.x*wv.z; acc0.w += xv.x*wv.w;
            acc1.x += xv.y*wv.x; acc1.y += xv.y*wv.y; acc1.z += xv.y*wv.z; acc1.w += xv.y*wv.w;
            acc2.x += xv.z*wv.x; acc2.y += xv.z*wv.y; acc2.z += xv.z*wv.z; acc2.w += xv.z*wv.w;
            acc3.x += xv.w*wv.x; acc3.y += xv.w*wv.y; acc3.z += xv.w*wv.z; acc3.w += xv.w*wv.w;
        }
        __syncthreads();
    }
    float* nr = nhpart + (size_t)(ky * 32 + bb * 4) * 1024 + n0 + nn * 4;
    *(float4*)(nr           ) = acc0;
    *(float4*)(nr + 1024    ) = acc1;
    *(float4*)(nr + 1024 * 2) = acc2;
    *(float4*)(nr + 1024 * 3) = acc3;
}

// ---------------- K4: nh = tanh(Σ16 partials + b) + vocab proj. 256 blocks = (b, v-octet):
// redundant per-block nh reduce (16 MB total, BW-bound ~3us) but every CU active.
__global__ void __launch_bounds__(256) k_nh_out(
    const float* __restrict__ nhpart, const float* __restrict__ concat_b,
    const float* __restrict__ out_w, const float* __restrict__ out_b,
    float* __restrict__ d_out)
{
    __shared__ float nhl[1024];
    int u = blockIdx.x;
    int b = u >> 3, vg = u & 7;
    int t = threadIdx.x;
    #pragma unroll
    for (int j = 0; j < 4; ++j) {
        int n = t + j * 256;
        float v = concat_b[n];
        #pragma unroll
        for (int s = 0; s < 16; ++s) v += nhpart[(size_t)(s * 32 + b) * 1024 + n];
        nhl[n] = tanhf(v);
    }
    __syncthreads();
    int w = t >> 6, lane = t & 63;
    const float* nr = nhl + lane * 4;
    #pragma unroll
    for (int vv = 0; vv < 2; ++vv) {
        int v = vg * 8 + w * 2 + vv;
        const float* wr = out_w + v * 1024 + lane * 4;
        float acc = 0.f;
        #pragma unroll
        for (int i = 0; i < 4; ++i) {
            float4 wv = *(const float4*)(wr + i * 256);
            float4 nv = *(const float4*)(nr + i * 256);
            acc += dot4(wv, nv);
        }
        #pragma unroll
        for (int off = 32; off > 0; off >>= 1) acc += __shfl_xor(acc, off, 64);
        if (lane == 0) d_out[b * 64 + v] = acc + out_b[v];
    }
}

extern "C" void kernel_launch(void* const* d_in, const int* in_sizes, int n_in,
                              void* d_out, int out_size, void* d_ws, size_t ws_size,
                              hipStream_t stream)
{
    const int*   chars    = (const int*)  d_in[0];
    const float* h_prev   = (const float*)d_in[1];
    const float* c_prev   = (const float*)d_in[2];
    const int*   lens     = (const int*)  d_in[3];
    const float* enc      = (const float*)d_in[4];
    const float* emb      = (const float*)d_in[5];
    const float* w_ih     = (const float*)d_in[6];
    const float* w_hh     = (const float*)d_in[7];
    const float* b_ih     = (const float*)d_in[8];
    const float* b_hh     = (const float*)d_in[9];
    const float* attn_w   = (const float*)d_in[10];
    const float* concat_w = (const float*)d_in[12];
    const float* concat_b = (const float*)d_in[13];
    const float* out_w    = (const float*)d_in[14];
    const float* out_b    = (const float*)d_in[15];
    float* out = (float*)d_out;

    float* ws = (float*)d_ws;
    float* zpart  = ws;                      // 8*32*4096   = 1048576
    float* xcat2  = zpart + 1048576;         // 32*2048     = 65536
    float* part   = xcat2 + 65536;           // 2048*RECF   = 2105344
    float* nhpart = part + 2105344;          // 16*32*1024  = 524288

    // K1: attention (strided rows, ~28.5us measured with gemm union) — r8 exact
    attn_gemm0<<<dim3(NATTN + 256), 256, 0, stream>>>(enc, lens, attn_w, part,
                                                      emb, chars, h_prev, w_ih, w_hh, zpart);
    // K2: LSTM gate epilogue ∪ attention record-combine (full-unroll) -> xcat2
    gates_combine<<<dim3(256), 256, 0, stream>>>(zpart, b_ih, b_hh, c_prev, part, out, xcat2);
    // K3: concat projection split-K partials
    gemm_concat<<<dim3(128), 256, 0, stream>>>(xcat2, concat_w, nhpart);
    // K4: nh reduce+tanh + vocab projection (256 blocks)
    k_nh_out<<<dim3(256), 256, 0, stream>>>(nhpart, concat_b, out_w, out_b, out);
}

// Round 15
// 51.616 us; speedup vs baseline: 2.8704x; 1.0226x over previous
//
#include <hip/hip_runtime.h>
#include <math.h>

#define NB    32
#define SEQ   2048
#define HD    1024
#define CDIM  256
#define NATTN 512
#define RECF  1028         // floats per partial record: 1024 ctx + 1 denom + pad (16B aligned)

__device__ __forceinline__ float dot4(float4 a, float4 b) {
    return a.x*b.x + a.y*b.y + a.z*b.z + a.w*b.w;
}

// ---------------- attention: wave w handles batch b=w&31, rows j, j+64, ... (j=w>>5).
// Measured r7/r13: ~23.3us alone, 28.5 with gemm0 union — streaming-bound. DO NOT TOUCH.
// Softmax h_new-independent (constant shift cancels); scores tiny -> exp(v) safe.
__device__ void attn_wave(int wid, const float* __restrict__ enc,
                          const int* __restrict__ lens, const float* __restrict__ attn_w,
                          float* __restrict__ part)
{
    int b = wid & 31, j = wid >> 5;
    int lane = threadIdx.x & 63;
    int len  = lens[b];

    float4 we0 = *(const float4*)(attn_w       + lane * 4);
    float4 we1 = *(const float4*)(attn_w + 256 + lane * 4);
    float4 we2 = *(const float4*)(attn_w + 512 + lane * 4);
    float4 we3 = *(const float4*)(attn_w + 768 + lane * 4);
    float4 c0 = make_float4(0,0,0,0), c1 = c0, c2 = c0, c3 = c0;
    float l = 0.f;

    const float* ebase = enc + (size_t)b * SEQ * HD + lane * 4;
    for (int s = j; s < len; s += 64) {
        const float* ep = ebase + (size_t)s * HD;
        float4 e0 = *(const float4*)(ep);
        float4 e1 = *(const float4*)(ep + 256);
        float4 e2 = *(const float4*)(ep + 512);
        float4 e3 = *(const float4*)(ep + 768);
        float v = dot4(e0,we0) + dot4(e1,we1) + dot4(e2,we2) + dot4(e3,we3);
        #pragma unroll
        for (int off = 32; off > 0; off >>= 1) v += __shfl_xor(v, off, 64);
        float p = __expf(v);
        l += p;
        c0.x += p*e0.x; c0.y += p*e0.y; c0.z += p*e0.z; c0.w += p*e0.w;
        c1.x += p*e1.x; c1.y += p*e1.y; c1.z += p*e1.z; c1.w += p*e1.w;
        c2.x += p*e2.x; c2.y += p*e2.y; c2.z += p*e2.z; c2.w += p*e2.w;
        c3.x += p*e3.x; c3.y += p*e3.y; c3.z += p*e3.z; c3.w += p*e3.w;
    }
    float* rec = part + (size_t)(b * 64 + j) * RECF;
    *(float4*)(rec +       lane * 4) = c0;
    *(float4*)(rec + 256 + lane * 4) = c1;
    *(float4*)(rec + 512 + lane * 4) = c2;
    *(float4*)(rec + 768 + lane * 4) = c3;
    if (lane == 0) rec[1024] = l;
}

// ---------------- gemm0 (LSTM): X=[emb|h_prev] 32x1280, W=[w_ih|w_hh] 4096x1280.
// Block = 32b x 128n, KSPLIT=8 (KRANGE=160) -> 256 units. Thread micro-tile 4b x 4n.
__device__ void gemm0_body(int gid,
                           const float* __restrict__ emb, const int* __restrict__ chars,
                           const float* __restrict__ h_prev,
                           const float* __restrict__ w_ih, const float* __restrict__ w_hh,
                           float* __restrict__ zpart)
{
    __shared__ float Xs[32][36];    // [k][b], pad keeps 16B alignment
    __shared__ float Ws[32][132];   // [k][n]

    const int nt = gid & 31;
    const int ky = gid >> 5;
    const int n0 = nt * 128;
    const int kbase = ky * 160;

    const int t  = threadIdx.x;
    const int nn = t & 31;
    const int bb = t >> 5;

    float4 acc0 = make_float4(0,0,0,0), acc1 = acc0, acc2 = acc0, acc3 = acc0;

    const int xb = t >> 3, xk = (t & 7) * 4;
    const int wn = t >> 3, wk = (t & 7) * 4;

    for (int k0 = kbase; k0 < kbase + 160; k0 += 32) {
        {
            int k = k0 + xk;
            float4 xv;
            if (k < CDIM) xv = *(const float4*)(emb + chars[xb] * CDIM + k);
            else          xv = *(const float4*)(h_prev + xb * HD + (k - CDIM));
            Xs[xk+0][xb] = xv.x; Xs[xk+1][xb] = xv.y; Xs[xk+2][xb] = xv.z; Xs[xk+3][xb] = xv.w;
        }
        #pragma unroll
        for (int i = 0; i < 4; ++i) {
            int n = n0 + wn + 32 * i;
            int k = k0 + wk;
            float4 wv;
            if (k < CDIM) wv = *(const float4*)(w_ih + n * CDIM + k);
            else          wv = *(const float4*)(w_hh + n * HD + (k - CDIM));
            int nc = wn + 32 * i;
            Ws[wk+0][nc] = wv.x; Ws[wk+1][nc] = wv.y; Ws[wk+2][nc] = wv.z; Ws[wk+3][nc] = wv.w;
        }
        __syncthreads();
        #pragma unroll
        for (int k = 0; k < 32; ++k) {
            float4 xv = *(const float4*)&Xs[k][bb * 4];
            float4 wv = *(const float4*)&Ws[k][nn * 4];
            acc0.x += xv.x*wv.x; acc0.y += xv.x*wv.y; acc0.z += xv.x*wv.z; acc0.w += xv.x*wv.w;
            acc1.x += xv.y*wv.x; acc1.y += xv.y*wv.y; acc1.z += xv.y*wv.z; acc1.w += xv.y*wv.w;
            acc2.x += xv.z*wv.x; acc2.y += xv.z*wv.y; acc2.z += xv.z*wv.z; acc2.w += xv.z*wv.w;
            acc3.x += xv.w*wv.x; acc3.y += xv.w*wv.y; acc3.z += xv.w*wv.z; acc3.w += xv.w*wv.w;
        }
        __syncthreads();
    }
    float* zr = zpart + (size_t)(ky * 32 + bb * 4) * 4096 + n0 + nn * 4;
    *(float4*)(zr           ) = acc0;
    *(float4*)(zr + 4096    ) = acc1;
    *(float4*)(zr + 4096 * 2) = acc2;
    *(float4*)(zr + 4096 * 3) = acc3;
}

// ---------------- K1: attn (blocks 0..511) ∪ LSTM gemm (blocks 512..767) — r8 exact
__global__ void __launch_bounds__(256) attn_gemm0(
    const float* __restrict__ enc, const int* __restrict__ lens,
    const float* __restrict__ attn_w, float* __restrict__ part,
    const float* __restrict__ emb, const int* __restrict__ chars,
    const float* __restrict__ h_prev,
    const float* __restrict__ w_ih, const float* __restrict__ w_hh,
    float* __restrict__ zpart)
{
    if (blockIdx.x < NATTN)
        attn_wave(blockIdx.x * 4 + (threadIdx.x >> 6), enc, lens, attn_w, part);
    else
        gemm0_body(blockIdx.x - NATTN, emb, chars, h_prev, w_ih, w_hh, zpart);
}

// ---------------- K2: LSTM gate epilogue (blocks 0..127) ∪ attention combine (128..255)
__global__ void gates_combine(const float* __restrict__ zpart,
                              const float* __restrict__ b_ih, const float* __restrict__ b_hh,
                              const float* __restrict__ c_prev, const float* __restrict__ part,
                              float* __restrict__ d_out, float* __restrict__ xcat2)
{
    int t = threadIdx.x;
    if (blockIdx.x < 128) {
        int idx = blockIdx.x * 256 + t;           // 32*1024
        int b = idx >> 10, j = idx & 1023;
        float z[4];
        #pragma unroll
        for (int g = 0; g < 4; ++g) {
            int n = g * 1024 + j;
            float v = b_ih[n] + b_hh[n];
            #pragma unroll
            for (int s = 0; s < 8; ++s) v += zpart[(size_t)(s * 32 + b) * 4096 + n];
            z[g] = v;
        }
        float gi = 1.f / (1.f + __expf(-z[0]));
        float gf = 1.f / (1.f + __expf(-z[1]));
        float gg = tanhf(z[2]);
        float go = 1.f / (1.f + __expf(-z[3]));
        float c = gf * c_prev[idx] + gi * gg;
        float h = go * tanhf(c);
        d_out[2048 + idx]         = h;            // h_new
        d_out[2048 + 32768 + idx] = c;            // c_new
        xcat2[b * 2048 + 1024 + j] = h;
    } else {
        int bid = blockIdx.x - 128;
        int b = bid >> 2, slice = bid & 3;
        int hh = slice * 256 + t;
        const float* recbase = part + (size_t)b * 64 * RECF;
        float a0 = 0.f, a1 = 0.f, a2 = 0.f, a3 = 0.f;
        float l0 = 0.f, l1 = 0.f, l2 = 0.f, l3 = 0.f;
        #pragma unroll
        for (int i = 0; i < 64; i += 4) {         // fully unrolled, 8 parallel accumulators
            a0 += recbase[(size_t)(i+0) * RECF + hh];
            a1 += recbase[(size_t)(i+1) * RECF + hh];
            a2 += recbase[(size_t)(i+2) * RECF + hh];
            a3 += recbase[(size_t)(i+3) * RECF + hh];
            l0 += recbase[(size_t)(i+0) * RECF + 1024];
            l1 += recbase[(size_t)(i+1) * RECF + 1024];
            l2 += recbase[(size_t)(i+2) * RECF + 1024];
            l3 += recbase[(size_t)(i+3) * RECF + 1024];
        }
        xcat2[b * 2048 + hh] = (a0 + a1 + a2 + a3) / (l0 + l1 + l2 + l3);
    }
}

// ---------------- K3: concat projection split-K, SOFTWARE-PIPELINED.
// Prefetch iter t+1's global tiles into regs before iter t's compute barrier -> HBM
// latency overlaps compute instead of serializing (4 exposed rounds -> ~1).
__global__ void __launch_bounds__(256) gemm_concat(
    const float* __restrict__ xcat2, const float* __restrict__ concat_w,
    float* __restrict__ nhpart)
{
    __shared__ float Xs[32][36];
    __shared__ float Ws[32][132];

    const int gid = blockIdx.x;
    const int nt = gid & 7;
    const int ky = gid >> 3;
    const int n0 = nt * 128;
    const int kbase = ky * 128;

    const int t  = threadIdx.x;
    const int nn = t & 31;
    const int bb = t >> 5;

    float4 acc0 = make_float4(0,0,0,0), acc1 = acc0, acc2 = acc0, acc3 = acc0;

    const int xb = t >> 3, xk = (t & 7) * 4;
    const int wn = t >> 3, wk = (t & 7) * 4;

    // prefetch iteration 0
    float4 xv_p = *(const float4*)(xcat2 + xb * 2048 + kbase + xk);
    float4 wv_p[4];
    #pragma unroll
    for (int i = 0; i < 4; ++i)
        wv_p[i] = *(const float4*)(concat_w + (n0 + wn + 32 * i) * 2048 + kbase + wk);

    #pragma unroll
    for (int it = 0; it < 4; ++it) {
        // write staged regs -> LDS
        Xs[xk+0][xb] = xv_p.x; Xs[xk+1][xb] = xv_p.y; Xs[xk+2][xb] = xv_p.z; Xs[xk+3][xb] = xv_p.w;
        #pragma unroll
        for (int i = 0; i < 4; ++i) {
            int nc = wn + 32 * i;
            Ws[wk+0][nc] = wv_p[i].x; Ws[wk+1][nc] = wv_p[i].y;
            Ws[wk+2][nc] = wv_p[i].z; Ws[wk+3][nc] = wv_p[i].w;
        }
        __syncthreads();
        // issue next iteration's loads (in flight during compute)
        if (it < 3) {
            int k0n = kbase + (it + 1) * 32;
            xv_p = *(const float4*)(xcat2 + xb * 2048 + k0n + xk);
            #pragma unroll
            for (int i = 0; i < 4; ++i)
                wv_p[i] = *(const float4*)(concat_w + (n0 + wn + 32 * i) * 2048 + k0n + wk);
        }
        #pragma unroll
        for (int k = 0; k < 32; ++k) {
            float4 xv = *(const float4*)&Xs[k][bb * 4];
            float4 wv = *(const float4*)&Ws[k][nn * 4];
            acc0.x += xv.x*wv.x; acc0.y += xv.x*wv.y; acc0.z += xv.x*wv.z; acc0.w += xv.x*wv.w;
            acc1.x += xv.y*wv.x; acc1.y += xv.y*wv.y; acc1.z += xv.y*wv.z; acc1.w += xv.y*wv.w;
            acc2.x += xv.z*wv.x; acc2.y += xv.z*wv.y; acc2.z += xv.z*wv.z; acc2.w += xv.z*wv.w;
            acc3.x += xv.w*wv.x; acc3.y += xv.w*wv.y; acc3.z += xv.w*wv.z; acc3.w += xv.w*wv.w;
        }
        __syncthreads();
    }
    float* nr = nhpart + (size_t)(ky * 32 + bb * 4) * 1024 + n0 + nn * 4;
    *(float4*)(nr           ) = acc0;
    *(float4*)(nr + 1024    ) = acc1;
    *(float4*)(nr + 1024 * 2) = acc2;
    *(float4*)(nr + 1024 * 3) = acc3;
}

// ---------------- K4: nh = tanh(Σ16 partials + b) + vocab proj. 256 blocks = (b, v-octet).
__global__ void __launch_bounds__(256) k_nh_out(
    const float* __restrict__ nhpart, const float* __restrict__ concat_b,
    const float* __restrict__ out_w, const float* __restrict__ out_b,
    float* __restrict__ d_out)
{
    __shared__ float nhl[1024];
    int u = blockIdx.x;
    int b = u >> 3, vg = u & 7;
    int t = threadIdx.x;
    #pragma unroll
    for (int j = 0; j < 4; ++j) {
        int n = t + j * 256;
        float v = concat_b[n];
        #pragma unroll
        for (int s = 0; s < 16; ++s) v += nhpart[(size_t)(s * 32 + b) * 1024 + n];
        nhl[n] = tanhf(v);
    }
    __syncthreads();
    int w = t >> 6, lane = t & 63;
    const float* nr = nhl + lane * 4;
    #pragma unroll
    for (int vv = 0; vv < 2; ++vv) {
        int v = vg * 8 + w * 2 + vv;
        const float* wr = out_w + v * 1024 + lane * 4;
        float acc = 0.f;
        #pragma unroll
        for (int i = 0; i < 4; ++i) {
            float4 wv = *(const float4*)(wr + i * 256);
            float4 nv = *(const float4*)(nr + i * 256);
            acc += dot4(wv, nv);
        }
        #pragma unroll
        for (int off = 32; off > 0; off >>= 1) acc += __shfl_xor(acc, off, 64);
        if (lane == 0) d_out[b * 64 + v] = acc + out_b[v];
    }
}

extern "C" void kernel_launch(void* const* d_in, const int* in_sizes, int n_in,
                              void* d_out, int out_size, void* d_ws, size_t ws_size,
                              hipStream_t stream)
{
    const int*   chars    = (const int*)  d_in[0];
    const float* h_prev   = (const float*)d_in[1];
    const float* c_prev   = (const float*)d_in[2];
    const int*   lens     = (const int*)  d_in[3];
    const float* enc      = (const float*)d_in[4];
    const float* emb      = (const float*)d_in[5];
    const float* w_ih     = (const float*)d_in[6];
    const float* w_hh     = (const float*)d_in[7];
    const float* b_ih     = (const float*)d_in[8];
    const float* b_hh     = (const float*)d_in[9];
    const float* attn_w   = (const float*)d_in[10];
    const float* concat_w = (const float*)d_in[12];
    const float* concat_b = (const float*)d_in[13];
    const float* out_w    = (const float*)d_in[14];
    const float* out_b    = (const float*)d_in[15];
    float* out = (float*)d_out;

    float* ws = (float*)d_ws;
    float* zpart  = ws;                      // 8*32*4096   = 1048576
    float* xcat2  = zpart + 1048576;         // 32*2048     = 65536
    float* part   = xcat2 + 65536;           // 2048*RECF   = 2105344
    float* nhpart = part + 2105344;          // 16*32*1024  = 524288

    // K1: attention (strided rows, ~28.5us measured with gemm union) — r8 exact
    attn_gemm0<<<dim3(NATTN + 256), 256, 0, stream>>>(enc, lens, attn_w, part,
                                                      emb, chars, h_prev, w_ih, w_hh, zpart);
    // K2: LSTM gate epilogue ∪ attention record-combine (full-unroll) -> xcat2
    gates_combine<<<dim3(256), 256, 0, stream>>>(zpart, b_ih, b_hh, c_prev, part, out, xcat2);
    // K3: concat projection split-K partials (software-pipelined)
    gemm_concat<<<dim3(128), 256, 0, stream>>>(xcat2, concat_w, nhpart);
    // K4: nh reduce+tanh + vocab projection (256 blocks)
    k_nh_out<<<dim3(256), 256, 0, stream>>>(nhpart, concat_b, out_w, out_b, out);
}

// Round 16
// 49.419 us; speedup vs baseline: 2.9980x; 1.0445x over previous
//
#include <hip/hip_runtime.h>
#include <math.h>

#define NB    32
#define SEQ   2048
#define HD    1024
#define CDIM  256
#define NATTN 512
#define RECU  516          // uints per partial record: 1024 bf16 ctx (512u) + f32 denom + pad

__device__ __forceinline__ float dot4(float4 a, float4 b) {
    return a.x*b.x + a.y*b.y + a.z*b.z + a.w*b.w;
}
__device__ __forceinline__ unsigned short f2bf(float f) {   // RNE float->bf16
    unsigned int u = __float_as_uint(f);
    u += 0x7FFFu + ((u >> 16) & 1u);
    return (unsigned short)(u >> 16);
}
__device__ __forceinline__ float bf2f(unsigned short s) {
    return __uint_as_float(((unsigned int)s) << 16);
}

// ---------------- attention: wave w handles batch b=w&31, rows j, j+64, ... (j=w>>5).
// Measured r7/r13: ~23.3us alone, 28.5 with gemm0 union — streaming-bound. Loop UNTOUCHED.
// Softmax h_new-independent (constant shift cancels); scores tiny -> exp(v) safe.
// Epilogue stores ctx partials as bf16 (r16): halves record traffic, error ~0.4% rel.
__device__ void attn_wave(int wid, const float* __restrict__ enc,
                          const int* __restrict__ lens, const float* __restrict__ attn_w,
                          unsigned int* __restrict__ partU)
{
    int b = wid & 31, j = wid >> 5;
    int lane = threadIdx.x & 63;
    int len  = lens[b];

    float4 we0 = *(const float4*)(attn_w       + lane * 4);
    float4 we1 = *(const float4*)(attn_w + 256 + lane * 4);
    float4 we2 = *(const float4*)(attn_w + 512 + lane * 4);
    float4 we3 = *(const float4*)(attn_w + 768 + lane * 4);
    float4 c0 = make_float4(0,0,0,0), c1 = c0, c2 = c0, c3 = c0;
    float l = 0.f;

    const float* ebase = enc + (size_t)b * SEQ * HD + lane * 4;
    for (int s = j; s < len; s += 64) {
        const float* ep = ebase + (size_t)s * HD;
        float4 e0 = *(const float4*)(ep);
        float4 e1 = *(const float4*)(ep + 256);
        float4 e2 = *(const float4*)(ep + 512);
        float4 e3 = *(const float4*)(ep + 768);
        float v = dot4(e0,we0) + dot4(e1,we1) + dot4(e2,we2) + dot4(e3,we3);
        #pragma unroll
        for (int off = 32; off > 0; off >>= 1) v += __shfl_xor(v, off, 64);
        float p = __expf(v);
        l += p;
        c0.x += p*e0.x; c0.y += p*e0.y; c0.z += p*e0.z; c0.w += p*e0.w;
        c1.x += p*e1.x; c1.y += p*e1.y; c1.z += p*e1.z; c1.w += p*e1.w;
        c2.x += p*e2.x; c2.y += p*e2.y; c2.z += p*e2.z; c2.w += p*e2.w;
        c3.x += p*e3.x; c3.y += p*e3.y; c3.z += p*e3.z; c3.w += p*e3.w;
    }
    unsigned short* rec = (unsigned short*)(partU + (size_t)(b * 64 + j) * RECU);
    *(ushort4*)(rec +       lane * 4) = make_ushort4(f2bf(c0.x), f2bf(c0.y), f2bf(c0.z), f2bf(c0.w));
    *(ushort4*)(rec + 256 + lane * 4) = make_ushort4(f2bf(c1.x), f2bf(c1.y), f2bf(c1.z), f2bf(c1.w));
    *(ushort4*)(rec + 512 + lane * 4) = make_ushort4(f2bf(c2.x), f2bf(c2.y), f2bf(c2.z), f2bf(c2.w));
    *(ushort4*)(rec + 768 + lane * 4) = make_ushort4(f2bf(c3.x), f2bf(c3.y), f2bf(c3.z), f2bf(c3.w));
    if (lane == 0) *(float*)(rec + 1024) = l;
}

// ---------------- gemm0 (LSTM): X=[emb|h_prev] 32x1280, W=[w_ih|w_hh] 4096x1280.
// Block = 32b x 128n, KSPLIT=8 (KRANGE=160) -> 256 units. Thread micro-tile 4b x 4n.
__device__ void gemm0_body(int gid,
                           const float* __restrict__ emb, const int* __restrict__ chars,
                           const float* __restrict__ h_prev,
                           const float* __restrict__ w_ih, const float* __restrict__ w_hh,
                           float* __restrict__ zpart)
{
    __shared__ float Xs[32][36];    // [k][b], pad keeps 16B alignment
    __shared__ float Ws[32][132];   // [k][n]

    const int nt = gid & 31;
    const int ky = gid >> 5;
    const int n0 = nt * 128;
    const int kbase = ky * 160;

    const int t  = threadIdx.x;
    const int nn = t & 31;
    const int bb = t >> 5;

    float4 acc0 = make_float4(0,0,0,0), acc1 = acc0, acc2 = acc0, acc3 = acc0;

    const int xb = t >> 3, xk = (t & 7) * 4;
    const int wn = t >> 3, wk = (t & 7) * 4;

    for (int k0 = kbase; k0 < kbase + 160; k0 += 32) {
        {
            int k = k0 + xk;
            float4 xv;
            if (k < CDIM) xv = *(const float4*)(emb + chars[xb] * CDIM + k);
            else          xv = *(const float4*)(h_prev + xb * HD + (k - CDIM));
            Xs[xk+0][xb] = xv.x; Xs[xk+1][xb] = xv.y; Xs[xk+2][xb] = xv.z; Xs[xk+3][xb] = xv.w;
        }
        #pragma unroll
        for (int i = 0; i < 4; ++i) {
            int n = n0 + wn + 32 * i;
            int k = k0 + wk;
            float4 wv;
            if (k < CDIM) wv = *(const float4*)(w_ih + n * CDIM + k);
            else          wv = *(const float4*)(w_hh + n * HD + (k - CDIM));
            int nc = wn + 32 * i;
            Ws[wk+0][nc] = wv.x; Ws[wk+1][nc] = wv.y; Ws[wk+2][nc] = wv.z; Ws[wk+3][nc] = wv.w;
        }
        __syncthreads();
        #pragma unroll
        for (int k = 0; k < 32; ++k) {
            float4 xv = *(const float4*)&Xs[k][bb * 4];
            float4 wv = *(const float4*)&Ws[k][nn * 4];
            acc0.x += xv.x*wv.x; acc0.y += xv.x*wv.y; acc0.z += xv.x*wv.z; acc0.w += xv.x*wv.w;
            acc1.x += xv.y*wv.x; acc1.y += xv.y*wv.y; acc1.z += xv.y*wv.z; acc1.w += xv.y*wv.w;
            acc2.x += xv.z*wv.x; acc2.y += xv.z*wv.y; acc2.z += xv.z*wv.z; acc2.w += xv.z*wv.w;
            acc3.x += xv.w*wv.x; acc3.y += xv.w*wv.y; acc3.z += xv.w*wv.z; acc3.w += xv.w*wv.w;
        }
        __syncthreads();
    }
    float* zr = zpart + (size_t)(ky * 32 + bb * 4) * 4096 + n0 + nn * 4;
    *(float4*)(zr           ) = acc0;
    *(float4*)(zr + 4096    ) = acc1;
    *(float4*)(zr + 4096 * 2) = acc2;
    *(float4*)(zr + 4096 * 3) = acc3;
}

// ---------------- K1: attn (blocks 0..511) ∪ LSTM gemm (blocks 512..767) — r8 layout
__global__ void __launch_bounds__(256) attn_gemm0(
    const float* __restrict__ enc, const int* __restrict__ lens,
    const float* __restrict__ attn_w, unsigned int* __restrict__ partU,
    const float* __restrict__ emb, const int* __restrict__ chars,
    const float* __restrict__ h_prev,
    const float* __restrict__ w_ih, const float* __restrict__ w_hh,
    float* __restrict__ zpart)
{
    if (blockIdx.x < NATTN)
        attn_wave(blockIdx.x * 4 + (threadIdx.x >> 6), enc, lens, attn_w, partU);
    else
        gemm0_body(blockIdx.x - NATTN, emb, chars, h_prev, w_ih, w_hh, zpart);
}

// ---------------- K2: LSTM gate epilogue (blocks 0..127) ∪ attention combine (128..255)
__global__ void gates_combine(const float* __restrict__ zpart,
                              const float* __restrict__ b_ih, const float* __restrict__ b_hh,
                              const float* __restrict__ c_prev,
                              const unsigned int* __restrict__ partU,
                              float* __restrict__ d_out, float* __restrict__ xcat2)
{
    int t = threadIdx.x;
    if (blockIdx.x < 128) {
        int idx = blockIdx.x * 256 + t;           // 32*1024
        int b = idx >> 10, j = idx & 1023;
        float z[4];
        #pragma unroll
        for (int g = 0; g < 4; ++g) {
            int n = g * 1024 + j;
            float v = b_ih[n] + b_hh[n];
            #pragma unroll
            for (int s = 0; s < 8; ++s) v += zpart[(size_t)(s * 32 + b) * 4096 + n];
            z[g] = v;
        }
        float gi = 1.f / (1.f + __expf(-z[0]));
        float gf = 1.f / (1.f + __expf(-z[1]));
        float gg = tanhf(z[2]);
        float go = 1.f / (1.f + __expf(-z[3]));
        float c = gf * c_prev[idx] + gi * gg;
        float h = go * tanhf(c);
        d_out[2048 + idx]         = h;            // h_new
        d_out[2048 + 32768 + idx] = c;            // c_new
        xcat2[b * 2048 + 1024 + j] = h;
    } else {
        int bid = blockIdx.x - 128;
        int b = bid >> 2, slice = bid & 3;
        int hh = slice * 256 + t;
        const unsigned int* pbase = partU + (size_t)b * 64 * RECU;
        float a0 = 0.f, a1 = 0.f, a2 = 0.f, a3 = 0.f;
        float l0 = 0.f, l1 = 0.f, l2 = 0.f, l3 = 0.f;
        #pragma unroll
        for (int i = 0; i < 64; i += 4) {         // fully unrolled, 8 parallel accumulators
            const unsigned short* r0 = (const unsigned short*)(pbase + (size_t)(i+0) * RECU);
            const unsigned short* r1 = (const unsigned short*)(pbase + (size_t)(i+1) * RECU);
            const unsigned short* r2 = (const unsigned short*)(pbase + (size_t)(i+2) * RECU);
            const unsigned short* r3 = (const unsigned short*)(pbase + (size_t)(i+3) * RECU);
            a0 += bf2f(r0[hh]);  l0 += *(const float*)(r0 + 1024);
            a1 += bf2f(r1[hh]);  l1 += *(const float*)(r1 + 1024);
            a2 += bf2f(r2[hh]);  l2 += *(const float*)(r2 + 1024);
            a3 += bf2f(r3[hh]);  l3 += *(const float*)(r3 + 1024);
        }
        xcat2[b * 2048 + hh] = (a0 + a1 + a2 + a3) / (l0 + l1 + l2 + l3);
    }
}

// ---------------- K3: concat projection split-K, pipelined, 256 blocks (r16 retile):
// 16 n-tiles of 64 x 16 k-splits of 128. Thread micro-tile 2b x 4n. W read exactly once.
__global__ void __launch_bounds__(256) gemm_concat(
    const float* __restrict__ xcat2, const float* __restrict__ concat_w,
    float* __restrict__ nhpart)
{
    __shared__ float Xs[32][36];
    __shared__ float Ws[32][68];

    const int gid = blockIdx.x;
    const int nt = gid & 15;
    const int ky = gid >> 4;
    const int n0 = nt * 64;
    const int kbase = ky * 128;

    const int t  = threadIdx.x;
    const int nn = t & 15;            // n = n0 + nn*4
    const int bb = t >> 4;            // b = bb*2

    float4 acc0 = make_float4(0,0,0,0), acc1 = acc0;

    const int xb = t >> 3, xk = (t & 7) * 4;
    const int wn = t >> 2, wk = (t & 3) * 8;

    // prefetch iteration 0
    float4 xv_p  = *(const float4*)(xcat2 + xb * 2048 + kbase + xk);
    float4 wv_p0 = *(const float4*)(concat_w + (n0 + wn) * 2048 + kbase + wk);
    float4 wv_p1 = *(const float4*)(concat_w + (n0 + wn) * 2048 + kbase + wk + 4);

    #pragma unroll
    for (int it = 0; it < 4; ++it) {
        Xs[xk+0][xb] = xv_p.x; Xs[xk+1][xb] = xv_p.y; Xs[xk+2][xb] = xv_p.z; Xs[xk+3][xb] = xv_p.w;
        Ws[wk+0][wn] = wv_p0.x; Ws[wk+1][wn] = wv_p0.y; Ws[wk+2][wn] = wv_p0.z; Ws[wk+3][wn] = wv_p0.w;
        Ws[wk+4][wn] = wv_p1.x; Ws[wk+5][wn] = wv_p1.y; Ws[wk+6][wn] = wv_p1.z; Ws[wk+7][wn] = wv_p1.w;
        __syncthreads();
        if (it < 3) {                 // next iteration's loads in flight during compute
            int k0n = kbase + (it + 1) * 32;
            xv_p  = *(const float4*)(xcat2 + xb * 2048 + k0n + xk);
            wv_p0 = *(const float4*)(concat_w + (n0 + wn) * 2048 + k0n + wk);
            wv_p1 = *(const float4*)(concat_w + (n0 + wn) * 2048 + k0n + wk + 4);
        }
        #pragma unroll
        for (int k = 0; k < 32; ++k) {
            float2 xv = *(const float2*)&Xs[k][bb * 2];
            float4 wv = *(const float4*)&Ws[k][nn * 4];
            acc0.x += xv.x*wv.x; acc0.y += xv.x*wv.y; acc0.z += xv.x*wv.z; acc0.w += xv.x*wv.w;
            acc1.x += xv.y*wv.x; acc1.y += xv.y*wv.y; acc1.z += xv.y*wv.z; acc1.w += xv.y*wv.w;
        }
        __syncthreads();
    }
    float* nr = nhpart + (size_t)(ky * 32 + bb * 2) * 1024 + n0 + nn * 4;
    *(float4*)(nr       ) = acc0;
    *(float4*)(nr + 1024) = acc1;
}

// ---------------- K4: nh = tanh(Σ16 partials + b) + vocab proj. 256 blocks = (b, v-octet).
__global__ void __launch_bounds__(256) k_nh_out(
    const float* __restrict__ nhpart, const float* __restrict__ concat_b,
    const float* __restrict__ out_w, const float* __restrict__ out_b,
    float* __restrict__ d_out)
{
    __shared__ float nhl[1024];
    int u = blockIdx.x;
    int b = u >> 3, vg = u & 7;
    int t = threadIdx.x;
    #pragma unroll
    for (int j = 0; j < 4; ++j) {
        int n = t + j * 256;
        float v = concat_b[n];
        #pragma unroll
        for (int s = 0; s < 16; ++s) v += nhpart[(size_t)(s * 32 + b) * 1024 + n];
        nhl[n] = tanhf(v);
    }
    __syncthreads();
    int w = t >> 6, lane = t & 63;
    const float* nr = nhl + lane * 4;
    #pragma unroll
    for (int vv = 0; vv < 2; ++vv) {
        int v = vg * 8 + w * 2 + vv;
        const float* wr = out_w + v * 1024 + lane * 4;
        float acc = 0.f;
        #pragma unroll
        for (int i = 0; i < 4; ++i) {
            float4 wv = *(const float4*)(wr + i * 256);
            float4 nv = *(const float4*)(nr + i * 256);
            acc += dot4(wv, nv);
        }
        #pragma unroll
        for (int off = 32; off > 0; off >>= 1) acc += __shfl_xor(acc, off, 64);
        if (lane == 0) d_out[b * 64 + v] = acc + out_b[v];
    }
}

extern "C" void kernel_launch(void* const* d_in, const int* in_sizes, int n_in,
                              void* d_out, int out_size, void* d_ws, size_t ws_size,
                              hipStream_t stream)
{
    const int*   chars    = (const int*)  d_in[0];
    const float* h_prev   = (const float*)d_in[1];
    const float* c_prev   = (const float*)d_in[2];
    const int*   lens     = (const int*)  d_in[3];
    const float* enc      = (const float*)d_in[4];
    const float* emb      = (const float*)d_in[5];
    const float* w_ih     = (const float*)d_in[6];
    const float* w_hh     = (const float*)d_in[7];
    const float* b_ih     = (const float*)d_in[8];
    const float* b_hh     = (const float*)d_in[9];
    const float* attn_w   = (const float*)d_in[10];
    const float* concat_w = (const float*)d_in[12];
    const float* concat_b = (const float*)d_in[13];
    const float* out_w    = (const float*)d_in[14];
    const float* out_b    = (const float*)d_in[15];
    float* out = (float*)d_out;

    float* ws = (float*)d_ws;
    float*        zpart  = ws;                       // 8*32*4096  = 1048576 floats
    float*        xcat2  = zpart + 1048576;          // 32*2048    = 65536
    unsigned int* partU  = (unsigned int*)(xcat2 + 65536);  // 2048*RECU = 1056768 uints
    float*        nhpart = (float*)(partU + 1056768);       // 16*32*1024 = 524288

    // K1: attention (strided rows, bf16 records) ∪ LSTM split-K gemm — loop identical to r8
    attn_gemm0<<<dim3(NATTN + 256), 256, 0, stream>>>(enc, lens, attn_w, partU,
                                                      emb, chars, h_prev, w_ih, w_hh, zpart);
    // K2: LSTM gate epilogue ∪ attention record-combine (bf16 reads) -> xcat2
    gates_combine<<<dim3(256), 256, 0, stream>>>(zpart, b_ih, b_hh, c_prev, partU, out, xcat2);
    // K3: concat projection split-K partials (pipelined, 256 blocks)
    gemm_concat<<<dim3(256), 256, 0, stream>>>(xcat2, concat_w, nhpart);
    // K4: nh reduce+tanh + vocab projection (256 blocks)
    k_nh_out<<<dim3(256), 256, 0, stream>>>(nhpart, concat_b, out_w, out_b, out);
}